// Round 4
// baseline (256.527 us; speedup 1.0000x reference)
//
#include <hip/hip_runtime.h>

#define SL 256

typedef _Float16 f16;
typedef _Float16 f16x8 __attribute__((ext_vector_type(8)));
typedef _Float16 f16x4 __attribute__((ext_vector_type(4)));
typedef float f32x4 __attribute__((ext_vector_type(4)));

// ---------------------------------------------------------------------------
// Filter MLP: one block per (l, sel); sel=0 -> X params, sel=1 -> Y params.
// Writes transposed f16 filters hT[sel][d][l] for fast R-table builds.
// ---------------------------------------------------------------------------
__global__ __launch_bounds__(64) void k_filters(
    const float* __restrict__ z,
    const float* __restrict__ Xw1, const float* __restrict__ Xb1,
    const float* __restrict__ Xw2, const float* __restrict__ Xb2,
    const float* __restrict__ Xw3, const float* __restrict__ Xb3,
    const float* __restrict__ Xwo, const float* __restrict__ Xfreq,
    const float* __restrict__ Yw1, const float* __restrict__ Yb1,
    const float* __restrict__ Yw2, const float* __restrict__ Yb2,
    const float* __restrict__ Yw3, const float* __restrict__ Yb3,
    const float* __restrict__ Ywo, const float* __restrict__ Yfreq,
    f16* __restrict__ hxT, f16* __restrict__ hyT)
{
    const int l = blockIdx.x;
    const int sel = blockIdx.y;
    const int t = threadIdx.x;
    const float* w1 = sel ? Yw1 : Xw1;  const float* b1 = sel ? Yb1 : Xb1;
    const float* w2 = sel ? Yw2 : Xw2;  const float* b2 = sel ? Yb2 : Xb2;
    const float* w3 = sel ? Yw3 : Xw3;  const float* b3 = sel ? Yb3 : Xb3;
    const float* wo = sel ? Ywo : Xwo;  const float* freq = sel ? Yfreq : Xfreq;
    f16* hT = sel ? hyT : hxT;

    __shared__ float zb[33];
    __shared__ float ha[64];
    __shared__ float hb[64];

    if (t < 33) zb[t] = z[l * 33 + t];
    __syncthreads();

    const float fr = freq[t];
    float s = b1[t];
    for (int k = 0; k < 33; ++k) s += zb[k] * w1[k * 64 + t];
    ha[t] = sinf(fr * s);
    __syncthreads();

    s = b2[t];
    for (int k = 0; k < 64; ++k) s += ha[k] * w2[k * 64 + t];
    hb[t] = sinf(fr * s);
    __syncthreads();

    s = b3[t];
    for (int k = 0; k < 64; ++k) s += hb[k] * w3[k * 64 + t];
    ha[t] = sinf(fr * s);
    __syncthreads();

    s = 0.f;
    for (int k = 0; k < 64; ++k) s += ha[k] * wo[k * 64 + t];

    const float MIN_DEC = -3.0701134573253937f;   // log(0.01)/1.5
    const float MAX_DEC = -15.350567286626968f;   // log(0.01)/0.3
    float ad = fabsf(MIN_DEC + (MAX_DEC - MIN_DEC) * ((float)t / 63.0f));
    float tl = (float)l / 255.0f;
    hT[t * 256 + l] = (f16)(s * expf(-tl * ad));   // [d][l]
}

__device__ __forceinline__ f16x8 cvt8(float4 a, float4 b)
{
    f16x8 h;
    h[0] = (f16)a.x; h[1] = (f16)a.y; h[2] = (f16)a.z; h[3] = (f16)a.w;
    h[4] = (f16)b.x; h[5] = (f16)b.y; h[6] = (f16)b.z; h[7] = (f16)b.w;
    return h;
}

// ---------------------------------------------------------------------------
// Fused, 1024 threads (16 waves, 4/SIMD): one block per (b,d).
// R-copy Toeplitz tables (8 shift-staggered copies of reversed zero-padded
// filter) for hy and hx are built up front -> 2 barriers total.
// Phase 1: M[p][j] = sum_q x[p][q]*hy[j-q] -> LDS tmp (f16, XOR swizzle).
//   waves = 16 p-groups (16 rows each, all 256 j): x read ONCE per block,
//   distance-3 prefetch (6 KB/CU in flight).
// Phase 2: D[j][i] = sum_p tmp[j][p]*hx[i-p]; epilogue x prefetched under
//   the K-loop; out[i][j..j+3] = D/512 + x*bias as float4.
// ---------------------------------------------------------------------------
__global__ __launch_bounds__(1024, 4) void k_fused(
    const float* __restrict__ x, const f16* __restrict__ hxT,
    const f16* __restrict__ hyT, const float* __restrict__ bias,
    float* __restrict__ out)
{
    const int bd = blockIdx.x;          // b*64 + d
    const int d  = bd & 63;
    const int tid  = threadIdx.x;
    const int lane = tid & 63;
    const int wave = tid >> 6;
    const int ln   = lane & 15;
    const int quad = lane >> 4;

    __shared__ __align__(16) f16 tmp[256 * 256];   // [j][p ^ ((j&7)<<3)]
    __shared__ __align__(16) f16 Ry[8 * 520];
    __shared__ __align__(16) f16 Rx[8 * 520];

    const float* xbd = x + (size_t)bd * (SL * SL);
    const float* xrow = xbd + (wave * 16 + ln) * SL + quad * 8;

    // issue first phase-1 x loads immediately (overlap with R builds)
    float4 pfa[8], pfb[8];
#pragma unroll
    for (int s = 0; s < 3; ++s) {
        pfa[s] = *(const float4*)(xrow + s * 32);
        pfb[s] = *(const float4*)(xrow + s * 32 + 4);
    }

    // build both R tables: R[c*520+k] = Rfull[k+c], Rfull[u]=h[255-u] (0 pad)
    const f16* hyc = hyT + d * 256;
    const f16* hxc = hxT + d * 256;
    for (int idx = tid; idx < 8 * 520; idx += 1024) {
        int c = idx / 520;
        int k = idx - c * 520;
        int u = k + c;
        f16 vy = (f16)0.f, vx = (f16)0.f;
        if (u <= 255) { vy = hyc[255 - u]; vx = hxc[255 - u]; }
        Ry[idx] = vy;
        Rx[idx] = vx;
    }

    f32x4 acc[16];
#pragma unroll
    for (int a = 0; a < 16; ++a) acc[a] = (f32x4){0.f, 0.f, 0.f, 0.f};

    __syncthreads();   // R tables ready

    // ---------------- Phase 1: wave owns p = wave*16+ln rows, all j --------
#pragma unroll
    for (int s = 0; s < 8; ++s) {
        const int q0 = s * 32;
        if (s + 3 < 8) {
            pfa[s + 3] = *(const float4*)(xrow + (s + 3) * 32);
            pfb[s + 3] = *(const float4*)(xrow + (s + 3) * 32 + 4);
        }
        f16x8 af = cvt8(pfa[s], pfb[s]);
#pragma unroll
        for (int h = 0; h < 2; ++h) {
            f16x8 bf[8];
#pragma unroll
            for (int c8 = 0; c8 < 8; ++c8) {
                int j = (h * 8 + c8) * 16 + ln;
                int s0 = 255 - j + q0 + quad * 8;
                int c = s0 & 7;
                bf[c8] = *(const f16x8*)&Ry[c * 520 + (s0 - c)];
            }
#pragma unroll
            for (int c8 = 0; c8 < 8; ++c8)
                acc[h * 8 + c8] = __builtin_amdgcn_mfma_f32_16x16x32_f16(
                    af, bf[c8], acc[h * 8 + c8], 0, 0, 0);
        }
    }

    // write M to LDS: element (j,p) at tmp[j*256 + (p ^ ((j&7)<<3))]
    {
        const int pb = wave * 16 + quad * 4;
#pragma unroll
        for (int ct = 0; ct < 16; ++ct) {
            int j = ct * 16 + ln;
            f32x4 a = acc[ct];
            f16x4 v;
            v[0] = (f16)a[0]; v[1] = (f16)a[1];
            v[2] = (f16)a[2]; v[3] = (f16)a[3];
            *(f16x4*)&tmp[j * 256 + (pb ^ ((j & 7) << 3))] = v;
        }
    }

    __syncthreads();   // tmp complete

#pragma unroll
    for (int a = 0; a < 16; ++a) acc[a] = (f32x4){0.f, 0.f, 0.f, 0.f};

    // ---------------- Phase 2: D[j][i], waves = 4(i) x 4(j) ----------------
    const int wii = wave & 3;
    const int wjj = wave >> 2;

    // prefetch epilogue x for i-groups 0,1 (latency hidden under K-loop)
    float4 xpf[8];
#pragma unroll
    for (int g = 0; g < 2; ++g)
#pragma unroll
        for (int rt = 0; rt < 4; ++rt)
            xpf[g * 4 + rt] = *(const float4*)(xbd
                + (wii * 64 + g * 16 + ln) * SL + wjj * 64 + rt * 16 + quad * 4);

    for (int p0 = 0; p0 < 256; p0 += 32) {
        f16x8 af[4];
#pragma unroll
        for (int rt = 0; rt < 4; ++rt) {          // A = tmp[j][p]
            int j = wjj * 64 + rt * 16 + ln;
            int off = (p0 + quad * 8) ^ ((j & 7) << 3);
            af[rt] = *(const f16x8*)&tmp[j * 256 + off];
        }
#pragma unroll
        for (int ct = 0; ct < 4; ++ct) {          // B[p][i] = hx[i-p]
            int i = wii * 64 + ct * 16 + ln;
            int s0 = 255 - i + p0 + quad * 8;
            int c = s0 & 7;
            f16x8 bf = *(const f16x8*)&Rx[c * 520 + (s0 - c)];
#pragma unroll
            for (int rt = 0; rt < 4; ++rt)
                acc[rt * 4 + ct] = __builtin_amdgcn_mfma_f32_16x16x32_f16(
                    af[rt], bf, acc[rt * 4 + ct], 0, 0, 0);
        }
    }

    // prefetch epilogue x for i-groups 2,3
    float4 xp2[8];
#pragma unroll
    for (int g = 0; g < 2; ++g)
#pragma unroll
        for (int rt = 0; rt < 4; ++rt)
            xp2[g * 4 + rt] = *(const float4*)(xbd
                + (wii * 64 + (g + 2) * 16 + ln) * SL + wjj * 64 + rt * 16 + quad * 4);

    // epilogue: out[i][jb..jb+3] = acc/512 + x*bias  (float4, coalesced)
    const float bv = bias[d];
    const float sc = 1.0f / 512.0f;
    float* obd = out + (size_t)bd * (SL * SL);
#pragma unroll
    for (int g = 0; g < 2; ++g)
#pragma unroll
        for (int rt = 0; rt < 4; ++rt) {
            int i  = wii * 64 + g * 16 + ln;
            int jb = wjj * 64 + rt * 16 + quad * 4;
            f32x4 a = acc[rt * 4 + g];
            float4 xv = xpf[g * 4 + rt];
            float4 o;
            o.x = a[0] * sc + xv.x * bv;
            o.y = a[1] * sc + xv.y * bv;
            o.z = a[2] * sc + xv.z * bv;
            o.w = a[3] * sc + xv.w * bv;
            *(float4*)(obd + i * SL + jb) = o;
        }
#pragma unroll
    for (int g = 0; g < 2; ++g)
#pragma unroll
        for (int rt = 0; rt < 4; ++rt) {
            int i  = wii * 64 + (g + 2) * 16 + ln;
            int jb = wjj * 64 + rt * 16 + quad * 4;
            f32x4 a = acc[rt * 4 + (g + 2)];
            float4 xv = xp2[g * 4 + rt];
            float4 o;
            o.x = a[0] * sc + xv.x * bv;
            o.y = a[1] * sc + xv.y * bv;
            o.z = a[2] * sc + xv.z * bv;
            o.w = a[3] * sc + xv.w * bv;
            *(float4*)(obd + i * SL + jb) = o;
        }
}

extern "C" void kernel_launch(void* const* d_in, const int* in_sizes, int n_in,
                              void* d_out, int out_size, void* d_ws, size_t ws_size,
                              hipStream_t stream)
{
    (void)in_sizes; (void)n_in; (void)out_size; (void)ws_size;
    const float* x     = (const float*)d_in[0];
    const float* z     = (const float*)d_in[1];
    const float* Xw1   = (const float*)d_in[2];
    const float* Xb1   = (const float*)d_in[3];
    const float* Xw2   = (const float*)d_in[4];
    const float* Xb2   = (const float*)d_in[5];
    const float* Xw3   = (const float*)d_in[6];
    const float* Xb3   = (const float*)d_in[7];
    const float* Xwo   = (const float*)d_in[8];
    const float* Xfreq = (const float*)d_in[9];
    const float* Yw1   = (const float*)d_in[10];
    const float* Yb1   = (const float*)d_in[11];
    const float* Yw2   = (const float*)d_in[12];
    const float* Yb2   = (const float*)d_in[13];
    const float* Yw3   = (const float*)d_in[14];
    const float* Yb3   = (const float*)d_in[15];
    const float* Ywo   = (const float*)d_in[16];
    const float* Yfreq = (const float*)d_in[17];
    const float* bias  = (const float*)d_in[18];

    f16* hxT = (f16*)d_ws;                 // [64][256] f16
    f16* hyT = hxT + 64 * 256;             // [64][256] f16

    k_filters<<<dim3(256, 2), 64, 0, stream>>>(
        z, Xw1, Xb1, Xw2, Xb2, Xw3, Xb3, Xwo, Xfreq,
        Yw1, Yb1, Yw2, Yb2, Yw3, Yb3, Ywo, Yfreq, hxT, hyT);
    k_fused<<<256, 1024, 0, stream>>>(x, hxT, hyT, bias, (float*)d_out);
}

// Round 5
// 176.756 us; speedup vs baseline: 1.4513x; 1.4513x over previous
//
#include <hip/hip_runtime.h>

#define SL 256

typedef _Float16 f16;
typedef _Float16 f16x8 __attribute__((ext_vector_type(8)));
typedef _Float16 f16x4 __attribute__((ext_vector_type(4)));
typedef float f32x4 __attribute__((ext_vector_type(4)));

// ---------------------------------------------------------------------------
// Filter MLP: one block per (l, sel); sel=0 -> X params, sel=1 -> Y params.
// Writes transposed f16 filters hT[sel][d][l] for fast R-table builds.
// ---------------------------------------------------------------------------
__global__ __launch_bounds__(64) void k_filters(
    const float* __restrict__ z,
    const float* __restrict__ Xw1, const float* __restrict__ Xb1,
    const float* __restrict__ Xw2, const float* __restrict__ Xb2,
    const float* __restrict__ Xw3, const float* __restrict__ Xb3,
    const float* __restrict__ Xwo, const float* __restrict__ Xfreq,
    const float* __restrict__ Yw1, const float* __restrict__ Yb1,
    const float* __restrict__ Yw2, const float* __restrict__ Yb2,
    const float* __restrict__ Yw3, const float* __restrict__ Yb3,
    const float* __restrict__ Ywo, const float* __restrict__ Yfreq,
    f16* __restrict__ hxT, f16* __restrict__ hyT)
{
    const int l = blockIdx.x;
    const int sel = blockIdx.y;
    const int t = threadIdx.x;
    const float* w1 = sel ? Yw1 : Xw1;  const float* b1 = sel ? Yb1 : Xb1;
    const float* w2 = sel ? Yw2 : Xw2;  const float* b2 = sel ? Yb2 : Xb2;
    const float* w3 = sel ? Yw3 : Xw3;  const float* b3 = sel ? Yb3 : Xb3;
    const float* wo = sel ? Ywo : Xwo;  const float* freq = sel ? Yfreq : Xfreq;
    f16* hT = sel ? hyT : hxT;

    __shared__ float zb[33];
    __shared__ float ha[64];
    __shared__ float hb[64];

    if (t < 33) zb[t] = z[l * 33 + t];
    __syncthreads();

    const float fr = freq[t];
    float s = b1[t];
    for (int k = 0; k < 33; ++k) s += zb[k] * w1[k * 64 + t];
    ha[t] = sinf(fr * s);
    __syncthreads();

    s = b2[t];
    for (int k = 0; k < 64; ++k) s += ha[k] * w2[k * 64 + t];
    hb[t] = sinf(fr * s);
    __syncthreads();

    s = b3[t];
    for (int k = 0; k < 64; ++k) s += hb[k] * w3[k * 64 + t];
    ha[t] = sinf(fr * s);
    __syncthreads();

    s = 0.f;
    for (int k = 0; k < 64; ++k) s += ha[k] * wo[k * 64 + t];

    const float MIN_DEC = -3.0701134573253937f;   // log(0.01)/1.5
    const float MAX_DEC = -15.350567286626968f;   // log(0.01)/0.3
    float ad = fabsf(MIN_DEC + (MAX_DEC - MIN_DEC) * ((float)t / 63.0f));
    float tl = (float)l / 255.0f;
    hT[t * 256 + l] = (f16)(s * expf(-tl * ad));   // [d][l]
}

__device__ __forceinline__ f16x8 cvt8(float4 a, float4 b)
{
    f16x8 h;
    h[0] = (f16)a.x; h[1] = (f16)a.y; h[2] = (f16)a.z; h[3] = (f16)a.w;
    h[4] = (f16)b.x; h[5] = (f16)b.y; h[6] = (f16)b.z; h[7] = (f16)b.w;
    return h;
}

// ---------------------------------------------------------------------------
// R-copy Toeplitz table: 8 shift-staggered copies of reversed zero-padded
// filter column so every Toeplitz fragment is one aligned ds_read_b128.
//   Rfull[u] = (u<=255) ? h[255-u] : 0 ;  R[c*520+k] = Rfull[k+c]
// Fragment T[row][k] = h[row-k] = Rfull[255-row+k]:
//   s0 = 255-row+k0 ; c = s0&7 ; f16x8 at R[c*520 + (s0-c)]
// ---------------------------------------------------------------------------
__device__ __forceinline__ void build_R(f16* R, const f16* __restrict__ hc,
                                        int tid)
{
    for (int idx = tid; idx < 8 * 520; idx += 512) {
        int c = idx / 520;
        int k = idx - c * 520;
        int u = k + c;
        R[idx] = (u <= 255) ? hc[255 - u] : (f16)0.f;
    }
}

// ---------------------------------------------------------------------------
// Fused, j-split: grid = 512 blocks of 512 threads (8 waves).
//   bd = blockIdx.x & 255, j-half = blockIdx.x >> 8 (same XCD for both
//   halves of a bd -> x L2/L3 reuse). LDS/block = 72 KB -> 2 blocks/CU:
//   one block's LDS-bound phase 2 overlaps the other's HBM phases.
// Phase 1: M[p][jl] = sum_q x[p][q]*hy[j0+jl-q], tmp 128x256 f16, XOR swz.
//   Causality: half 0 only needs q<128 (4 K-steps), half 1 needs 8.
//   Wave owns 32 p-rows, all 128 jl; x read once; distance-1 prefetch.
// Phase 2: D[jl][i] = sum_p tmp[jl][p]*hx[i-p]; epilogue float4:
//   out[i][j0+jl..+3] = D/512 + x*bias.
// ---------------------------------------------------------------------------
__global__ __launch_bounds__(512, 4) void k_fused(
    const float* __restrict__ x, const f16* __restrict__ hxT,
    const f16* __restrict__ hyT, const float* __restrict__ bias,
    float* __restrict__ out)
{
    const int bd = blockIdx.x & 255;        // b*64 + d
    const int j0 = (blockIdx.x >> 8) << 7;  // 0 or 128
    const int d  = bd & 63;
    const int tid  = threadIdx.x;
    const int lane = tid & 63;
    const int wave = tid >> 6;
    const int ln   = lane & 15;
    const int quad = lane >> 4;

    __shared__ __align__(16) f16 tmp[128 * 256];   // [jl][p ^ ((jl&7)<<3)]
    __shared__ __align__(16) f16 R[8 * 520];

    const float* xbd = x + (size_t)bd * (SL * SL);

    build_R(R, hyT + d * 256, tid);

    f32x4 acc[16];
#pragma unroll
    for (int a = 0; a < 16; ++a) acc[a] = (f32x4){0.f, 0.f, 0.f, 0.f};

    __syncthreads();   // R(hy) ready

    // ---------------- Phase 1: wave owns p rows [wave*32, wave*32+32) ------
    {
        const int qsteps = j0 ? 8 : 4;
        const float* xr0 = xbd + (wave * 32 + ln) * SL + quad * 8;
        const float* xr1 = xr0 + 16 * SL;

        float4 a0 = *(const float4*)xr0;
        float4 a1 = *(const float4*)(xr0 + 4);
        float4 b0 = *(const float4*)xr1;
        float4 b1 = *(const float4*)(xr1 + 4);

        for (int s = 0; s < qsteps; ++s) {
            const int q0 = s * 32;
            f16x8 af0 = cvt8(a0, a1);
            f16x8 af1 = cvt8(b0, b1);
            if (s + 1 < qsteps) {
                a0 = *(const float4*)(xr0 + q0 + 32);
                a1 = *(const float4*)(xr0 + q0 + 36);
                b0 = *(const float4*)(xr1 + q0 + 32);
                b1 = *(const float4*)(xr1 + q0 + 36);
            }
#pragma unroll
            for (int h = 0; h < 2; ++h) {
                f16x8 bf[4];
#pragma unroll
                for (int c4 = 0; c4 < 4; ++c4) {
                    int j = j0 + (h * 4 + c4) * 16 + ln;
                    int s0 = 255 - j + q0 + quad * 8;
                    int c = s0 & 7;
                    bf[c4] = *(const f16x8*)&R[c * 520 + (s0 - c)];
                }
#pragma unroll
                for (int c4 = 0; c4 < 4; ++c4) {
                    acc[h * 4 + c4] = __builtin_amdgcn_mfma_f32_16x16x32_f16(
                        af0, bf[c4], acc[h * 4 + c4], 0, 0, 0);
                    acc[8 + h * 4 + c4] = __builtin_amdgcn_mfma_f32_16x16x32_f16(
                        af1, bf[c4], acc[8 + h * 4 + c4], 0, 0, 0);
                }
            }
        }

        // write M to LDS: (jl, p) at tmp[jl*256 + (p ^ ((jl&7)<<3))]
#pragma unroll
        for (int r = 0; r < 2; ++r)
#pragma unroll
            for (int c8 = 0; c8 < 8; ++c8) {
                int jl = c8 * 16 + ln;
                int pb = wave * 32 + r * 16 + quad * 4;
                f32x4 a = acc[r * 8 + c8];
                f16x4 v;
                v[0] = (f16)a[0]; v[1] = (f16)a[1];
                v[2] = (f16)a[2]; v[3] = (f16)a[3];
                *(f16x4*)&tmp[jl * 256 + (pb ^ ((jl & 7) << 3))] = v;
            }
    }

    __syncthreads();   // tmp complete, R(hy) reads done
    build_R(R, hxT + d * 256, tid);
#pragma unroll
    for (int a = 0; a < 16; ++a) acc[a] = (f32x4){0.f, 0.f, 0.f, 0.f};
    __syncthreads();   // R(hx) ready

    // ---------------- Phase 2: D[jl][i], waves = 4(i) x 2(j) ---------------
    const int igrp = wave & 3;
    const int jgrp = wave >> 2;
#pragma unroll
    for (int p0 = 0; p0 < 256; p0 += 32) {
        f16x8 af[4];
#pragma unroll
        for (int rt = 0; rt < 4; ++rt) {          // A = tmp[jl][p]
            int jl = jgrp * 64 + rt * 16 + ln;
            int off = (p0 + quad * 8) ^ ((jl & 7) << 3);
            af[rt] = *(const f16x8*)&tmp[jl * 256 + off];
        }
#pragma unroll
        for (int ct = 0; ct < 4; ++ct) {          // B[p][i] = hx[i-p]
            int i = igrp * 64 + ct * 16 + ln;
            int s0 = 255 - i + p0 + quad * 8;
            int c = s0 & 7;
            f16x8 bf = *(const f16x8*)&R[c * 520 + (s0 - c)];
#pragma unroll
            for (int rt = 0; rt < 4; ++rt)
                acc[rt * 4 + ct] = __builtin_amdgcn_mfma_f32_16x16x32_f16(
                    af[rt], bf, acc[rt * 4 + ct], 0, 0, 0);
        }
    }

    // epilogue: out[i][j..j+3] = acc/512 + x*bias  (float4, coalesced)
    const float bv = bias[d];
    const float sc = 1.0f / 512.0f;
    float* obd = out + (size_t)bd * (SL * SL);
#pragma unroll
    for (int rt = 0; rt < 4; ++rt)
#pragma unroll
        for (int ct = 0; ct < 4; ++ct) {
            int i = igrp * 64 + ct * 16 + ln;
            int j = j0 + jgrp * 64 + rt * 16 + quad * 4;
            f32x4 a = acc[rt * 4 + ct];
            float4 xv = *(const float4*)(xbd + i * SL + j);
            float4 o;
            o.x = a[0] * sc + xv.x * bv;
            o.y = a[1] * sc + xv.y * bv;
            o.z = a[2] * sc + xv.z * bv;
            o.w = a[3] * sc + xv.w * bv;
            *(float4*)(obd + i * SL + j) = o;
        }
}

extern "C" void kernel_launch(void* const* d_in, const int* in_sizes, int n_in,
                              void* d_out, int out_size, void* d_ws, size_t ws_size,
                              hipStream_t stream)
{
    (void)in_sizes; (void)n_in; (void)out_size; (void)ws_size;
    const float* x     = (const float*)d_in[0];
    const float* z     = (const float*)d_in[1];
    const float* Xw1   = (const float*)d_in[2];
    const float* Xb1   = (const float*)d_in[3];
    const float* Xw2   = (const float*)d_in[4];
    const float* Xb2   = (const float*)d_in[5];
    const float* Xw3   = (const float*)d_in[6];
    const float* Xb3   = (const float*)d_in[7];
    const float* Xwo   = (const float*)d_in[8];
    const float* Xfreq = (const float*)d_in[9];
    const float* Yw1   = (const float*)d_in[10];
    const float* Yb1   = (const float*)d_in[11];
    const float* Yw2   = (const float*)d_in[12];
    const float* Yb2   = (const float*)d_in[13];
    const float* Yw3   = (const float*)d_in[14];
    const float* Yb3   = (const float*)d_in[15];
    const float* Ywo   = (const float*)d_in[16];
    const float* Yfreq = (const float*)d_in[17];
    const float* bias  = (const float*)d_in[18];

    f16* hxT = (f16*)d_ws;                 // [64][256] f16
    f16* hyT = hxT + 64 * 256;             // [64][256] f16

    k_filters<<<dim3(256, 2), 64, 0, stream>>>(
        z, Xw1, Xb1, Xw2, Xb2, Xw3, Xb3, Xwo, Xfreq,
        Yw1, Yb1, Yw2, Yb2, Yw3, Yb3, Ywo, Yfreq, hxT, hyT);
    k_fused<<<512, 512, 0, stream>>>(x, hxT, hyT, bias, (float*)d_out);
}